// Round 3
// baseline (724.451 us; speedup 1.0000x reference)
//
#include <hip/hip_runtime.h>
#include <hip/hip_bf16.h>

#define DDIM 128

typedef float    f32x16 __attribute__((ext_vector_type(16)));
typedef float    f32x4  __attribute__((ext_vector_type(4)));
typedef short    bf16x8 __attribute__((ext_vector_type(8)));
typedef __bf16   bf16x2t __attribute__((ext_vector_type(2)));
typedef unsigned u32x2  __attribute__((ext_vector_type(2)));
typedef unsigned u32x4  __attribute__((ext_vector_type(4)));

// hardware RNE f32->bf16 (compiler emits v_cvt_pk_bf16_f32 for pairs)
__device__ __forceinline__ unsigned pkbf(float a, float b) {
    bf16x2t v; v[0] = (__bf16)a; v[1] = (__bf16)b;
    return __builtin_bit_cast(unsigned, v);
}

__device__ __forceinline__ bf16x8 cvt8(f32x4 a, f32x4 b) {
    u32x4 u = { pkbf(a[0],a[1]), pkbf(a[2],a[3]), pkbf(b[0],b[1]), pkbf(b[2],b[3]) };
    return __builtin_bit_cast(bf16x8, u);
}

__device__ __forceinline__ void plswap(unsigned &x, unsigned &y) {
    u32x2 r = __builtin_amdgcn_permlane32_swap(x, y, false, false);
    x = r[0]; y = r[1];
}

__device__ __forceinline__ float silu(float x) {
    return x * __builtin_amdgcn_rcpf(1.0f + __expf(-x));
}

// ---- kernel 0: FRAGMENT-MAJOR bf16 weights (unchanged layout from R2).
// W1frag: [s(24)][n(128)][hi(2)][k8(8)], logical col = 16*s + 8*hi + k8 of [W_e|W_s|W_d].
// W2frag: [s(8)][n(128)][hi(2)][k8(8)], col = 16*s + 8*hi + k8 of w_out.
__global__ void prep_weights(const float* __restrict__ we, const float* __restrict__ wsrc,
                             const float* __restrict__ wdst, const float* __restrict__ wout,
                             short* __restrict__ w1frag, short* __restrict__ w2frag) {
    int tid = blockIdx.x * 256 + threadIdx.x;        // 65536 total
    if (tid < 24 * 128 * 16) {
        int k8 = tid & 7;
        int hi = (tid >> 3) & 1;
        int n  = (tid >> 4) & 127;
        int s  = tid >> 11;
        int col = 16 * s + 8 * hi + k8;              // 0..383
        const float* src = (col < 128) ? we : ((col < 256) ? wsrc : wdst);
        bf16x2t v; v[0] = (__bf16)src[n * 128 + (col & 127)]; v[1] = v[0];
        w1frag[tid] = (short)(__builtin_bit_cast(unsigned, v) & 0xffff);
    } else {
        int t2 = tid - 24 * 128 * 16;
        int k8 = t2 & 7;
        int hi = (t2 >> 3) & 1;
        int n  = (t2 >> 4) & 127;
        int s  = t2 >> 11;
        int col = 16 * s + 8 * hi + k8;              // 0..127
        bf16x2t v; v[0] = (__bf16)wout[n * 128 + col]; v[1] = v[0];
        w2frag[t2] = (short)(__builtin_bit_cast(unsigned, v) & 0xffff);
    }
}

// ---- fused edge kernel, TRANSPOSED GEMMs: h^T = W1cat . x^T ; y^T = W2 . silu(h)^T
// Each lane owns one edge (lo); D-layout leaves h/y lane-local (cols c with c%8 in [4hi,4hi+4)).
__global__ __launch_bounds__(256, 4) void edge_kernel(
    const float* __restrict__ efeat, const float* __restrict__ src_feat,
    const float* __restrict__ dst_feat, const int* __restrict__ src_idx,
    const int* __restrict__ dst_idx, const float* __restrict__ b0,
    const float* __restrict__ b_out, const float* __restrict__ ln_g,
    const float* __restrict__ ln_b, const short* __restrict__ w1frag,
    const short* __restrict__ w2frag, float* __restrict__ out, int E)
{
    const int tid  = threadIdx.x;
    const int wave = tid >> 6;
    const int lane = tid & 63;
    const int lo   = lane & 31;
    const int hi   = lane >> 5;

    const int erow = blockIdx.x * 128 + wave * 32 + lo;   // this lane's edge
    const int ecl  = erow < E ? erow : E - 1;
    const int sidx = src_idx[ecl];
    const int didx = dst_idx[ecl];
    const float* pe = efeat    + (size_t)ecl  * DDIM;
    const float* ps = src_feat + (size_t)sidx * DDIM;
    const float* pd = dst_feat + (size_t)didx * DDIM;

    const int coff  = 8 * hi;                 // k sub-offset within a 16-wide K step
    const int poff  = 4 * hi;                 // per-lane col sub-offset for params/output
    const int fslot = (lo * 2 + hi) * 8;      // weight A-fragment slot (shorts)

    // ---------------- GEMM1: acc[t] = h^T tile t (n rows 32t..32t+31, edges = cols) ----------------
    f32x16 acc[4];
#pragma unroll
    for (int t = 0; t < 4; ++t)
#pragma unroll
        for (int Q = 0; Q < 4; ++Q) {
            f32x4 bq = *(const f32x4*)(b0 + 32 * t + 8 * Q + poff);
            acc[t][4*Q+0] = bq[0]; acc[t][4*Q+1] = bq[1];
            acc[t][4*Q+2] = bq[2]; acc[t][4*Q+3] = bq[3];
        }

#pragma unroll
    for (int seg = 0; seg < 3; ++seg) {
        const float* p = (seg == 0) ? pe : ((seg == 1) ? ps : pd);
#pragma unroll
        for (int ks = 0; ks < 8; ++ks) {
            const f32x4* pv = (const f32x4*)(p + 16 * ks + coff);
            f32x4 fa, fb;
            if (seg == 0) { fa = __builtin_nontemporal_load(pv); fb = __builtin_nontemporal_load(pv + 1); }
            else          { fa = pv[0];                          fb = pv[1]; }
            bf16x8 x = cvt8(fa, fb);                     // B-fragment: x[edge lo][16s+8hi+j]
            const int s = seg * 8 + ks;
            const short* wb = w1frag + s * 2048 + fslot; // A-fragment: W1[32t+lo][16s+8hi+j]
#pragma unroll
            for (int t = 0; t < 4; ++t) {
                bf16x8 w = *(const bf16x8*)(wb + t * 512);
                acc[t] = __builtin_amdgcn_mfma_f32_32x32x16_bf16(w, x, acc[t], 0, 0, 0);
            }
        }
    }

    // ---------------- SiLU + pack to bf16, all lane-local ----------------
    // acc[t][4Q+j] = h[edge lo][c], c = 32t + 8Q + 4hi + j
    unsigned hbf[4][4][2];
#pragma unroll
    for (int t = 0; t < 4; ++t)
#pragma unroll
        for (int Q = 0; Q < 4; ++Q) {
            float h0 = silu(acc[t][4*Q+0]), h1 = silu(acc[t][4*Q+1]);
            float h2 = silu(acc[t][4*Q+2]), h3 = silu(acc[t][4*Q+3]);
            hbf[t][Q][0] = pkbf(h0, h1);
            hbf[t][Q][1] = pkbf(h2, h3);
        }

    // ---------------- GEMM2: y^T = W2 . silu(h)^T ----------------
    f32x16 acc2[4];
#pragma unroll
    for (int t = 0; t < 4; ++t)
#pragma unroll
        for (int Q = 0; Q < 4; ++Q) {
            f32x4 bq = *(const f32x4*)(b_out + 32 * t + 8 * Q + poff);
            acc2[t][4*Q+0] = bq[0]; acc2[t][4*Q+1] = bq[1];
            acc2[t][4*Q+2] = bq[2]; acc2[t][4*Q+3] = bq[3];
        }

#pragma unroll
    for (int s = 0; s < 8; ++s) {
        const int t  = s >> 1;
        const int q0 = (2 * s) & 3;          // quad holding k%8 = 0..3 (hi=0 lanes)
        const int q1 = q0 + 1;               // quad holding k%8 = 4..7 (hi=1 lanes)
        unsigned X0 = hbf[t][q0][0], X1 = hbf[t][q0][1];
        unsigned Y0 = hbf[t][q1][0], Y1 = hbf[t][q1][1];
        // exchange halves: lower lanes keep q0 & receive upper's q0; upper lanes get lower's q1 & keep q1
        plswap(X0, Y0);
        plswap(X1, Y1);
        u32x4 fv = { X0, X1, Y0, Y1 };       // B-fragment: h[edge lo][16s+8hi + 0..7]
        bf16x8 hf = __builtin_bit_cast(bf16x8, fv);
        const short* wb = w2frag + s * 2048 + fslot;
#pragma unroll
        for (int tt = 0; tt < 4; ++tt) {
            bf16x8 w = *(const bf16x8*)(wb + tt * 512);
            acc2[tt] = __builtin_amdgcn_mfma_f32_32x32x16_bf16(w, hf, acc2[tt], 0, 0, 0);
        }
    }

    // ---------------- LayerNorm: lane-local sums + one half-exchange ----------------
    float s1 = 0.f, s2 = 0.f;
#pragma unroll
    for (int t = 0; t < 4; ++t)
#pragma unroll
        for (int r = 0; r < 16; ++r) {
            float v = acc2[t][r];
            s1 += v;
            s2 = fmaf(v, v, s2);
        }
    s1 += __shfl_xor(s1, 32, 64);
    s2 += __shfl_xor(s2, 32, 64);
    const float mu   = s1 * (1.0f / 128.0f);
    const float var  = s2 * (1.0f / 128.0f) - mu * mu;
    const float rstd = rsqrtf(var + 1e-5f);

    if (erow < E) {
        float* po = out + (size_t)erow * DDIM;
#pragma unroll
        for (int t = 0; t < 4; ++t)
#pragma unroll
            for (int Q = 0; Q < 4; ++Q) {
                const int c = 32 * t + 8 * Q + poff;
                f32x4 g = *(const f32x4*)(ln_g + c);
                f32x4 b = *(const f32x4*)(ln_b + c);
                f32x4 o;
#pragma unroll
                for (int j = 0; j < 4; ++j)
                    o[j] = (acc2[t][4*Q+j] - mu) * rstd * g[j] + b[j];
                __builtin_nontemporal_store(o, (f32x4*)(po + c));
            }
    }
}

extern "C" void kernel_launch(void* const* d_in, const int* in_sizes, int n_in,
                              void* d_out, int out_size, void* d_ws, size_t ws_size,
                              hipStream_t stream)
{
    const float* efeat    = (const float*)d_in[0];
    const float* src_feat = (const float*)d_in[1];
    const float* dst_feat = (const float*)d_in[2];
    const int*   src_idx  = (const int*)d_in[3];
    const int*   dst_idx  = (const int*)d_in[4];
    const float* w_efeat  = (const float*)d_in[5];
    const float* w_src    = (const float*)d_in[6];
    const float* w_dst    = (const float*)d_in[7];
    const float* b0       = (const float*)d_in[8];
    const float* w_out    = (const float*)d_in[9];
    const float* b_out    = (const float*)d_in[10];
    const float* ln_g     = (const float*)d_in[11];
    const float* ln_b     = (const float*)d_in[12];
    float* out = (float*)d_out;
    const int E = in_sizes[3];

    short* w1frag = (short*)d_ws;                              // 24*128*16 bf16 = 96 KB
    short* w2frag = (short*)((char*)d_ws + 24 * 128 * 16 * 2); // 8*128*16 bf16 = 32 KB

    prep_weights<<<256, 256, 0, stream>>>(w_efeat, w_src, w_dst, w_out, w1frag, w2frag);

    const int nb = (E + 127) / 128;
    edge_kernel<<<nb, 256, 0, stream>>>(efeat, src_feat, dst_feat, src_idx, dst_idx,
                                        b0, b_out, ln_g, ln_b, w1frag, w2frag, out, E);
}

// Round 4
// 523.644 us; speedup vs baseline: 1.3835x; 1.3835x over previous
//
#include <hip/hip_runtime.h>
#include <hip/hip_bf16.h>

#define DDIM 128

typedef float    f32x16 __attribute__((ext_vector_type(16)));
typedef float    f32x4  __attribute__((ext_vector_type(4)));
typedef short    bf16x8 __attribute__((ext_vector_type(8)));
typedef __bf16   bf16x2t __attribute__((ext_vector_type(2)));
typedef unsigned u32x2  __attribute__((ext_vector_type(2)));
typedef unsigned u32x4  __attribute__((ext_vector_type(4)));

// hardware RNE f32->bf16 (compiler emits v_cvt_pk_bf16_f32 for pairs)
__device__ __forceinline__ unsigned pkbf(float a, float b) {
    bf16x2t v; v[0] = (__bf16)a; v[1] = (__bf16)b;
    return __builtin_bit_cast(unsigned, v);
}

__device__ __forceinline__ bf16x8 cvt8(f32x4 a, f32x4 b) {
    u32x4 u = { pkbf(a[0],a[1]), pkbf(a[2],a[3]), pkbf(b[0],b[1]), pkbf(b[2],b[3]) };
    return __builtin_bit_cast(bf16x8, u);
}

__device__ __forceinline__ void plswap(unsigned &x, unsigned &y) {
    u32x2 r = __builtin_amdgcn_permlane32_swap(x, y, false, false);
    x = r[0]; y = r[1];
}

__device__ __forceinline__ float silu(float x) {
    return x * __builtin_amdgcn_rcpf(1.0f + __expf(-x));
}

// ---- kernel 0: FRAGMENT-MAJOR bf16 weights (layout verified R2/R3).
// W1frag: [s(24)][n(128)][hi(2)][k8(8)], logical col = 16*s + 8*hi + k8 of [W_e|W_s|W_d].
// W2frag: [s(8)][n(128)][hi(2)][k8(8)], col = 16*s + 8*hi + k8 of w_out.
__global__ void prep_weights(const float* __restrict__ we, const float* __restrict__ wsrc,
                             const float* __restrict__ wdst, const float* __restrict__ wout,
                             short* __restrict__ w1frag, short* __restrict__ w2frag) {
    int tid = blockIdx.x * 256 + threadIdx.x;        // 65536 total
    if (tid < 24 * 128 * 16) {
        int k8 = tid & 7;
        int hi = (tid >> 3) & 1;
        int n  = (tid >> 4) & 127;
        int s  = tid >> 11;
        int col = 16 * s + 8 * hi + k8;              // 0..383
        const float* src = (col < 128) ? we : ((col < 256) ? wsrc : wdst);
        bf16x2t v; v[0] = (__bf16)src[n * 128 + (col & 127)]; v[1] = v[0];
        w1frag[tid] = (short)(__builtin_bit_cast(unsigned, v) & 0xffff);
    } else {
        int t2 = tid - 24 * 128 * 16;
        int k8 = t2 & 7;
        int hi = (t2 >> 3) & 1;
        int n  = (t2 >> 4) & 127;
        int s  = t2 >> 11;
        int col = 16 * s + 8 * hi + k8;              // 0..127
        bf16x2t v; v[0] = (__bf16)wout[n * 128 + col]; v[1] = v[0];
        w2frag[t2] = (short)(__builtin_bit_cast(unsigned, v) & 0xffff);
    }
}

// ---- fused edge kernel, hybrid:
//   GEMM1 transposed:  h^T = W1cat . x^T   (h lane-local -> SiLU/pack with no LDS)
//   GEMM2 straight:    y   = silu(h) @ W2^T (A-fragment built via permlane32_swap)
//   -> y lands in column-across-lanes layout -> coalesced stores + butterfly LN.
__global__ __launch_bounds__(256, 4) void edge_kernel(
    const float* __restrict__ efeat, const float* __restrict__ src_feat,
    const float* __restrict__ dst_feat, const int* __restrict__ src_idx,
    const int* __restrict__ dst_idx, const float* __restrict__ b0,
    const float* __restrict__ b_out, const float* __restrict__ ln_g,
    const float* __restrict__ ln_b, const short* __restrict__ w1frag,
    const short* __restrict__ w2frag, float* __restrict__ out, int E)
{
    const int tid  = threadIdx.x;
    const int wave = tid >> 6;
    const int lane = tid & 63;
    const int lo   = lane & 31;
    const int hi   = lane >> 5;
    const int ebase = blockIdx.x * 128 + wave * 32;

    const int erow = ebase + lo;              // this lane's edge (for loads / GEMM1)
    const int ecl  = erow < E ? erow : E - 1;
    const int sidx = src_idx[ecl];
    const int didx = dst_idx[ecl];
    const float* pe = efeat    + (size_t)ecl  * DDIM;
    const float* ps = src_feat + (size_t)sidx * DDIM;
    const float* pd = dst_feat + (size_t)didx * DDIM;

    const int coff  = 8 * hi;                 // k sub-offset within a 16-wide K step
    const int poff  = 4 * hi;                 // row sub-offset in transposed D-layout
    const int fslot = (lo * 2 + hi) * 8;      // weight fragment slot (shorts)

    // per-lane column params for GEMM2 output (col n = 32*tt + lo)
    float bov[4], gv[4], bv[4];
#pragma unroll
    for (int tt = 0; tt < 4; ++tt) {
        int n = 32 * tt + lo;
        bov[tt] = b_out[n]; gv[tt] = ln_g[n]; bv[tt] = ln_b[n];
    }

    // ---------------- GEMM1 (transposed): acc[t] rows = n, cols = edges; init b0 ----------------
    f32x16 acc[4];
#pragma unroll
    for (int t = 0; t < 4; ++t)
#pragma unroll
        for (int Q = 0; Q < 4; ++Q) {
            f32x4 bq = *(const f32x4*)(b0 + 32 * t + 8 * Q + poff);
            acc[t][4*Q+0] = bq[0]; acc[t][4*Q+1] = bq[1];
            acc[t][4*Q+2] = bq[2]; acc[t][4*Q+3] = bq[3];
        }

#pragma unroll
    for (int seg = 0; seg < 3; ++seg) {
        const float* p = (seg == 0) ? pe : ((seg == 1) ? ps : pd);
#pragma unroll
        for (int ks = 0; ks < 8; ++ks) {
            const f32x4* pv = (const f32x4*)(p + 16 * ks + coff);
            f32x4 fa, fb;
            if (seg == 0) { fa = __builtin_nontemporal_load(pv); fb = __builtin_nontemporal_load(pv + 1); }
            else          { fa = pv[0];                          fb = pv[1]; }
            bf16x8 x = cvt8(fa, fb);                     // B-fragment: x[edge lo][16s+8hi+j]
            const int s = seg * 8 + ks;
            const short* wb = w1frag + s * 2048 + fslot; // A-fragment: W1[32t+lo][16s+8hi+j]
#pragma unroll
            for (int t = 0; t < 4; ++t) {
                bf16x8 w = *(const bf16x8*)(wb + t * 512);
                acc[t] = __builtin_amdgcn_mfma_f32_32x32x16_bf16(w, x, acc[t], 0, 0, 0);
            }
        }
    }

    // ---------------- SiLU + pack to bf16, all lane-local ----------------
    // acc[t][4Q+j] = h[edge lo][c], c = 32t + 8Q + 4hi + j
    unsigned hbf[4][4][2];
#pragma unroll
    for (int t = 0; t < 4; ++t)
#pragma unroll
        for (int Q = 0; Q < 4; ++Q) {
            float h0 = silu(acc[t][4*Q+0]), h1 = silu(acc[t][4*Q+1]);
            float h2 = silu(acc[t][4*Q+2]), h3 = silu(acc[t][4*Q+3]);
            hbf[t][Q][0] = pkbf(h0, h1);
            hbf[t][Q][1] = pkbf(h2, h3);
        }

    // ---------------- GEMM2 (straight): y = silu(h) @ W2^T, D cols = n across lanes ----------------
    f32x16 acc2[4];
#pragma unroll
    for (int tt = 0; tt < 4; ++tt)
#pragma unroll
        for (int r = 0; r < 16; ++r) acc2[tt][r] = bov[tt];

#pragma unroll
    for (int s = 0; s < 8; ++s) {
        const int t  = s >> 1;
        const int q0 = (2 * s) & 3;          // quad holding k%8 = 0..3 (hi=0 lanes)
        const int q1 = q0 + 1;               // quad holding k%8 = 4..7 (hi=1 lanes)
        unsigned X0 = hbf[t][q0][0], X1 = hbf[t][q0][1];
        unsigned Y0 = hbf[t][q1][0], Y1 = hbf[t][q1][1];
        plswap(X0, Y0);                      // exchange halves across lane<32 / lane>=32
        plswap(X1, Y1);
        u32x4 fv = { X0, X1, Y0, Y1 };       // A-fragment: h[edge lo][16s+8hi + 0..7]
        bf16x8 hf = __builtin_bit_cast(bf16x8, fv);
        const short* wb = w2frag + s * 2048 + fslot;
#pragma unroll
        for (int tt = 0; tt < 4; ++tt) {
            bf16x8 w = *(const bf16x8*)(wb + tt * 512);  // B-fragment: W2[32tt+lo][16s+8hi+j]
            acc2[tt] = __builtin_amdgcn_mfma_f32_32x32x16_bf16(hf, w, acc2[tt], 0, 0, 0);
        }
    }

    // ---------------- LayerNorm (butterfly over 32 lanes) + coalesced store ----------------
#pragma unroll
    for (int r = 0; r < 16; ++r) {
        float s1 = acc2[0][r] + acc2[1][r] + acc2[2][r] + acc2[3][r];
        float s2 = acc2[0][r]*acc2[0][r] + acc2[1][r]*acc2[1][r]
                 + acc2[2][r]*acc2[2][r] + acc2[3][r]*acc2[3][r];
#pragma unroll
        for (int msk = 1; msk < 32; msk <<= 1) {
            s1 += __shfl_xor(s1, msk, 64);
            s2 += __shfl_xor(s2, msk, 64);
        }
        const float mu   = s1 * (1.0f / 128.0f);
        const float var  = s2 * (1.0f / 128.0f) - mu * mu;
        const float rstd = rsqrtf(var + 1e-5f);
        const int   m    = (r & 3) + 8 * (r >> 2) + 4 * hi;   // edge row within wave tile
        const int   eo   = ebase + m;
        if (eo < E) {
            float* po = out + (size_t)eo * DDIM;
#pragma unroll
            for (int tt = 0; tt < 4; ++tt) {
                float o = (acc2[tt][r] - mu) * rstd * gv[tt] + bv[tt];
                __builtin_nontemporal_store(o, po + 32 * tt + lo);
            }
        }
    }
}

extern "C" void kernel_launch(void* const* d_in, const int* in_sizes, int n_in,
                              void* d_out, int out_size, void* d_ws, size_t ws_size,
                              hipStream_t stream)
{
    const float* efeat    = (const float*)d_in[0];
    const float* src_feat = (const float*)d_in[1];
    const float* dst_feat = (const float*)d_in[2];
    const int*   src_idx  = (const int*)d_in[3];
    const int*   dst_idx  = (const int*)d_in[4];
    const float* w_efeat  = (const float*)d_in[5];
    const float* w_src    = (const float*)d_in[6];
    const float* w_dst    = (const float*)d_in[7];
    const float* b0       = (const float*)d_in[8];
    const float* w_out    = (const float*)d_in[9];
    const float* b_out    = (const float*)d_in[10];
    const float* ln_g     = (const float*)d_in[11];
    const float* ln_b     = (const float*)d_in[12];
    float* out = (float*)d_out;
    const int E = in_sizes[3];

    short* w1frag = (short*)d_ws;                              // 24*128*16 bf16 = 96 KB
    short* w2frag = (short*)((char*)d_ws + 24 * 128 * 16 * 2); // 8*128*16 bf16 = 32 KB

    prep_weights<<<256, 256, 0, stream>>>(w_efeat, w_src, w_dst, w_out, w1frag, w2frag);

    const int nb = (E + 127) / 128;
    edge_kernel<<<nb, 256, 0, stream>>>(efeat, src_feat, dst_feat, src_idx, dst_idx,
                                        b0, b_out, ln_g, ln_b, w1frag, w2frag, out, E);
}

// Round 5
// 516.254 us; speedup vs baseline: 1.4033x; 1.0143x over previous
//
#include <hip/hip_runtime.h>
#include <hip/hip_bf16.h>

#define DDIM 128

typedef float    f32x16 __attribute__((ext_vector_type(16)));
typedef float    f32x4  __attribute__((ext_vector_type(4)));
typedef short    bf16x8 __attribute__((ext_vector_type(8)));
typedef __bf16   bf16x2t __attribute__((ext_vector_type(2)));
typedef unsigned u32x2  __attribute__((ext_vector_type(2)));
typedef unsigned u32x4  __attribute__((ext_vector_type(4)));
typedef unsigned short us4 __attribute__((ext_vector_type(4)));

// hardware RNE f32->bf16 (compiler emits v_cvt_pk_bf16_f32 for pairs)
__device__ __forceinline__ unsigned pkbf(float a, float b) {
    bf16x2t v; v[0] = (__bf16)a; v[1] = (__bf16)b;
    return __builtin_bit_cast(unsigned, v);
}

__device__ __forceinline__ short f2bf16s(float a) {
    __bf16 b = (__bf16)a;
    return __builtin_bit_cast(short, b);
}

__device__ __forceinline__ float bf16tof(unsigned short u) {
    return __builtin_bit_cast(float, ((unsigned)u) << 16);
}

__device__ __forceinline__ bf16x8 cvt8(f32x4 a, f32x4 b) {
    u32x4 u = { pkbf(a[0],a[1]), pkbf(a[2],a[3]), pkbf(b[0],b[1]), pkbf(b[2],b[3]) };
    return __builtin_bit_cast(bf16x8, u);
}

__device__ __forceinline__ void plswap(unsigned &x, unsigned &y) {
    u32x2 r = __builtin_amdgcn_permlane32_swap(x, y, false, false);
    x = r[0]; y = r[1];
}

__device__ __forceinline__ float silu(float x) {
    return x * __builtin_amdgcn_rcpf(1.0f + __expf(-x));
}

// ---- kernel 0: FRAGMENT-MAJOR bf16 weights (layout verified R2-R4).
// W1frag: [s(24)][n(128)][hi(2)][k8(8)], logical col = 16*s + 8*hi + k8 of [W_e|W_s|W_d].
//   s=0..7 -> W_e cols, s=8..15 -> W_s, s=16..23 -> W_d.
// W2frag: [s(8)][n(128)][hi(2)][k8(8)], col = 16*s + 8*hi + k8 of w_out.
__global__ void prep_weights(const float* __restrict__ we, const float* __restrict__ wsrc,
                             const float* __restrict__ wdst, const float* __restrict__ wout,
                             short* __restrict__ w1frag, short* __restrict__ w2frag) {
    int tid = blockIdx.x * 256 + threadIdx.x;        // 65536 total
    if (tid < 24 * 128 * 16) {
        int k8 = tid & 7;
        int hi = (tid >> 3) & 1;
        int n  = (tid >> 4) & 127;
        int s  = tid >> 11;
        int col = 16 * s + 8 * hi + k8;              // 0..383
        const float* src = (col < 128) ? we : ((col < 256) ? wsrc : wdst);
        w1frag[tid] = f2bf16s(src[n * 128 + (col & 127)]);
    } else {
        int t2 = tid - 24 * 128 * 16;
        int k8 = t2 & 7;
        int hi = (t2 >> 3) & 1;
        int n  = (t2 >> 4) & 127;
        int s  = t2 >> 11;
        int col = 16 * s + 8 * hi + k8;              // 0..127
        w2frag[t2] = f2bf16s(wout[n * 128 + col]);
    }
}

// ---- node-table kernel: tbl[row] = feat[row] @ Wseg^T (bf16 output, no bias).
// Straight GEMM: A = feat fragment [row lo][16s+8hi+j], B = w1frag slice (segoff+s).
// D layout (verified R4 GEMM2): col = 32t+lo across lanes, row m = (r&3)+8(r>>2)+4hi.
__global__ __launch_bounds__(256, 4) void node_table(
    const float* __restrict__ feat, const short* __restrict__ w1frag,
    int segoff, short* __restrict__ tbl, int N)
{
    const int tid  = threadIdx.x;
    const int wave = tid >> 6;
    const int lane = tid & 63;
    const int lo   = lane & 31;
    const int hi   = lane >> 5;
    const int base = blockIdx.x * 128 + wave * 32;
    const int row  = base + lo;
    const int rcl  = row < N ? row : N - 1;
    const float* pn = feat + (size_t)rcl * DDIM;
    const int coff  = 8 * hi;
    const int fslot = (lo * 2 + hi) * 8;

    f32x16 acc[4];
#pragma unroll
    for (int t = 0; t < 4; ++t)
#pragma unroll
        for (int r = 0; r < 16; ++r) acc[t][r] = 0.0f;

#pragma unroll
    for (int s = 0; s < 8; ++s) {
        const f32x4* pv = (const f32x4*)(pn + 16 * s + coff);
        f32x4 fa = pv[0], fb = pv[1];
        bf16x8 a = cvt8(fa, fb);                       // A-frag: x[row lo][16s+8hi+j]
        const short* wb = w1frag + (segoff + s) * 2048 + fslot;
#pragma unroll
        for (int t = 0; t < 4; ++t) {
            bf16x8 w = *(const bf16x8*)(wb + t * 512);  // B-frag: W[32t+lo][16s+8hi+j]
            acc[t] = __builtin_amdgcn_mfma_f32_32x32x16_bf16(a, w, acc[t], 0, 0, 0);
        }
    }

#pragma unroll
    for (int r = 0; r < 16; ++r) {
        const int m = (r & 3) + 8 * (r >> 2) + 4 * hi;
        const int node = base + m;
        if (node < N) {
            short* po = tbl + (size_t)node * DDIM;
#pragma unroll
            for (int t = 0; t < 4; ++t)
                po[32 * t + lo] = f2bf16s(acc[t][r]);
        }
    }
}

// ---- fused edge kernel (table path):
//   GEMM1 transposed, K=128 (efeat only):  h^T = W_e . efeat^T  (+ b0 init)
//   gathered bf16 table rows added lane-locally (burst-issued before GEMM1)
//   SiLU/pack lane-local -> GEMM2 straight via permlane -> butterfly LN -> coalesced NT store.
__global__ __launch_bounds__(256, 3) void edge_kernel_tab(
    const float* __restrict__ efeat, const short* __restrict__ tsrc,
    const short* __restrict__ tdst, const int* __restrict__ src_idx,
    const int* __restrict__ dst_idx, const float* __restrict__ b0,
    const float* __restrict__ b_out, const float* __restrict__ ln_g,
    const float* __restrict__ ln_b, const short* __restrict__ w1frag,
    const short* __restrict__ w2frag, float* __restrict__ out, int E)
{
    const int tid  = threadIdx.x;
    const int wave = tid >> 6;
    const int lane = tid & 63;
    const int lo   = lane & 31;
    const int hi   = lane >> 5;
    const int ebase = blockIdx.x * 128 + wave * 32;

    const int erow = ebase + lo;              // this lane's edge
    const int ecl  = erow < E ? erow : E - 1;
    const int sidx = src_idx[ecl];
    const int didx = dst_idx[ecl];
    const float* pe = efeat + (size_t)ecl * DDIM;
    const short* prs = tsrc + (size_t)sidx * DDIM;
    const short* prd = tdst + (size_t)didx * DDIM;

    const int coff  = 8 * hi;                 // k sub-offset within a 16-wide K step
    const int poff  = 4 * hi;                 // row sub-offset in transposed D-layout
    const int fslot = (lo * 2 + hi) * 8;      // weight fragment slot (shorts)

    // ---- burst-issue the 32 gather loads (8B each); consumed after GEMM1 ----
    us4 tsv[16], tdv[16];
#pragma unroll
    for (int t = 0; t < 4; ++t)
#pragma unroll
        for (int Q = 0; Q < 4; ++Q) {
            const int c = 32 * t + 8 * Q + poff;
            tsv[t * 4 + Q] = *(const us4*)(prs + c);
            tdv[t * 4 + Q] = *(const us4*)(prd + c);
        }

    // per-lane column params for GEMM2 output (col n = 32*tt + lo)
    float bov[4], gv[4], bv[4];
#pragma unroll
    for (int tt = 0; tt < 4; ++tt) {
        int n = 32 * tt + lo;
        bov[tt] = b_out[n]; gv[tt] = ln_g[n]; bv[tt] = ln_b[n];
    }

    // ---- GEMM1 (transposed): acc[t] rows = n, cols = edges; init b0 ----
    f32x16 acc[4];
#pragma unroll
    for (int t = 0; t < 4; ++t)
#pragma unroll
        for (int Q = 0; Q < 4; ++Q) {
            f32x4 bq = *(const f32x4*)(b0 + 32 * t + 8 * Q + poff);
            acc[t][4*Q+0] = bq[0]; acc[t][4*Q+1] = bq[1];
            acc[t][4*Q+2] = bq[2]; acc[t][4*Q+3] = bq[3];
        }

#pragma unroll
    for (int s = 0; s < 8; ++s) {
        const f32x4* pv = (const f32x4*)(pe + 16 * s + coff);
        f32x4 fa = __builtin_nontemporal_load(pv);
        f32x4 fb = __builtin_nontemporal_load(pv + 1);
        bf16x8 x = cvt8(fa, fb);                     // B-frag: efeat[edge lo][16s+8hi+j]
        const short* wb = w1frag + s * 2048 + fslot; // A-frag: W_e[32t+lo][16s+8hi+j]
#pragma unroll
        for (int t = 0; t < 4; ++t) {
            bf16x8 w = *(const bf16x8*)(wb + t * 512);
            acc[t] = __builtin_amdgcn_mfma_f32_32x32x16_bf16(w, x, acc[t], 0, 0, 0);
        }
    }

    // ---- add gathered table rows (lane-local; c = 32t+8Q+4hi+j) ----
#pragma unroll
    for (int t = 0; t < 4; ++t)
#pragma unroll
        for (int Q = 0; Q < 4; ++Q) {
            us4 a = tsv[t * 4 + Q], d = tdv[t * 4 + Q];
#pragma unroll
            for (int j = 0; j < 4; ++j)
                acc[t][4*Q+j] += bf16tof(a[j]) + bf16tof(d[j]);
        }

    // ---- SiLU + pack to bf16, all lane-local ----
    unsigned hbf[4][4][2];
#pragma unroll
    for (int t = 0; t < 4; ++t)
#pragma unroll
        for (int Q = 0; Q < 4; ++Q) {
            float h0 = silu(acc[t][4*Q+0]), h1 = silu(acc[t][4*Q+1]);
            float h2 = silu(acc[t][4*Q+2]), h3 = silu(acc[t][4*Q+3]);
            hbf[t][Q][0] = pkbf(h0, h1);
            hbf[t][Q][1] = pkbf(h2, h3);
        }

    // ---- GEMM2 (straight): y = silu(h) @ W2^T ----
    f32x16 acc2[4];
#pragma unroll
    for (int tt = 0; tt < 4; ++tt)
#pragma unroll
        for (int r = 0; r < 16; ++r) acc2[tt][r] = bov[tt];

#pragma unroll
    for (int s = 0; s < 8; ++s) {
        const int t  = s >> 1;
        const int q0 = (2 * s) & 3;
        const int q1 = q0 + 1;
        unsigned X0 = hbf[t][q0][0], X1 = hbf[t][q0][1];
        unsigned Y0 = hbf[t][q1][0], Y1 = hbf[t][q1][1];
        plswap(X0, Y0);
        plswap(X1, Y1);
        u32x4 fv = { X0, X1, Y0, Y1 };       // A-frag: h[edge lo][16s+8hi + 0..7]
        bf16x8 hf = __builtin_bit_cast(bf16x8, fv);
        const short* wb = w2frag + s * 2048 + fslot;
#pragma unroll
        for (int tt = 0; tt < 4; ++tt) {
            bf16x8 w = *(const bf16x8*)(wb + tt * 512);
            acc2[tt] = __builtin_amdgcn_mfma_f32_32x32x16_bf16(hf, w, acc2[tt], 0, 0, 0);
        }
    }

    // ---- LayerNorm (butterfly over 32 lanes) + coalesced store ----
#pragma unroll
    for (int r = 0; r < 16; ++r) {
        float s1 = acc2[0][r] + acc2[1][r] + acc2[2][r] + acc2[3][r];
        float s2 = acc2[0][r]*acc2[0][r] + acc2[1][r]*acc2[1][r]
                 + acc2[2][r]*acc2[2][r] + acc2[3][r]*acc2[3][r];
#pragma unroll
        for (int msk = 1; msk < 32; msk <<= 1) {
            s1 += __shfl_xor(s1, msk, 64);
            s2 += __shfl_xor(s2, msk, 64);
        }
        const float mu   = s1 * (1.0f / 128.0f);
        const float var  = s2 * (1.0f / 128.0f) - mu * mu;
        const float rstd = rsqrtf(var + 1e-5f);
        const int   m    = (r & 3) + 8 * (r >> 2) + 4 * hi;
        const int   eo   = ebase + m;
        if (eo < E) {
            float* po = out + (size_t)eo * DDIM;
#pragma unroll
            for (int tt = 0; tt < 4; ++tt) {
                float o = (acc2[tt][r] - mu) * rstd * gv[tt] + bv[tt];
                __builtin_nontemporal_store(o, po + 32 * tt + lo);
            }
        }
    }
}

// ---- fallback: R4 full-K kernel (used only if ws can't hold the tables) ----
__global__ __launch_bounds__(256, 4) void edge_kernel_fullk(
    const float* __restrict__ efeat, const float* __restrict__ src_feat,
    const float* __restrict__ dst_feat, const int* __restrict__ src_idx,
    const int* __restrict__ dst_idx, const float* __restrict__ b0,
    const float* __restrict__ b_out, const float* __restrict__ ln_g,
    const float* __restrict__ ln_b, const short* __restrict__ w1frag,
    const short* __restrict__ w2frag, float* __restrict__ out, int E)
{
    const int tid  = threadIdx.x;
    const int wave = tid >> 6;
    const int lane = tid & 63;
    const int lo   = lane & 31;
    const int hi   = lane >> 5;
    const int ebase = blockIdx.x * 128 + wave * 32;

    const int erow = ebase + lo;
    const int ecl  = erow < E ? erow : E - 1;
    const int sidx = src_idx[ecl];
    const int didx = dst_idx[ecl];
    const float* pe = efeat    + (size_t)ecl  * DDIM;
    const float* ps = src_feat + (size_t)sidx * DDIM;
    const float* pd = dst_feat + (size_t)didx * DDIM;

    const int coff  = 8 * hi;
    const int poff  = 4 * hi;
    const int fslot = (lo * 2 + hi) * 8;

    float bov[4], gv[4], bv[4];
#pragma unroll
    for (int tt = 0; tt < 4; ++tt) {
        int n = 32 * tt + lo;
        bov[tt] = b_out[n]; gv[tt] = ln_g[n]; bv[tt] = ln_b[n];
    }

    f32x16 acc[4];
#pragma unroll
    for (int t = 0; t < 4; ++t)
#pragma unroll
        for (int Q = 0; Q < 4; ++Q) {
            f32x4 bq = *(const f32x4*)(b0 + 32 * t + 8 * Q + poff);
            acc[t][4*Q+0] = bq[0]; acc[t][4*Q+1] = bq[1];
            acc[t][4*Q+2] = bq[2]; acc[t][4*Q+3] = bq[3];
        }

#pragma unroll
    for (int seg = 0; seg < 3; ++seg) {
        const float* p = (seg == 0) ? pe : ((seg == 1) ? ps : pd);
#pragma unroll
        for (int ks = 0; ks < 8; ++ks) {
            const f32x4* pv = (const f32x4*)(p + 16 * ks + coff);
            f32x4 fa, fb;
            if (seg == 0) { fa = __builtin_nontemporal_load(pv); fb = __builtin_nontemporal_load(pv + 1); }
            else          { fa = pv[0];                          fb = pv[1]; }
            bf16x8 x = cvt8(fa, fb);
            const int s = seg * 8 + ks;
            const short* wb = w1frag + s * 2048 + fslot;
#pragma unroll
            for (int t = 0; t < 4; ++t) {
                bf16x8 w = *(const bf16x8*)(wb + t * 512);
                acc[t] = __builtin_amdgcn_mfma_f32_32x32x16_bf16(w, x, acc[t], 0, 0, 0);
            }
        }
    }

    unsigned hbf[4][4][2];
#pragma unroll
    for (int t = 0; t < 4; ++t)
#pragma unroll
        for (int Q = 0; Q < 4; ++Q) {
            float h0 = silu(acc[t][4*Q+0]), h1 = silu(acc[t][4*Q+1]);
            float h2 = silu(acc[t][4*Q+2]), h3 = silu(acc[t][4*Q+3]);
            hbf[t][Q][0] = pkbf(h0, h1);
            hbf[t][Q][1] = pkbf(h2, h3);
        }

    f32x16 acc2[4];
#pragma unroll
    for (int tt = 0; tt < 4; ++tt)
#pragma unroll
        for (int r = 0; r < 16; ++r) acc2[tt][r] = bov[tt];

#pragma unroll
    for (int s = 0; s < 8; ++s) {
        const int t  = s >> 1;
        const int q0 = (2 * s) & 3;
        const int q1 = q0 + 1;
        unsigned X0 = hbf[t][q0][0], X1 = hbf[t][q0][1];
        unsigned Y0 = hbf[t][q1][0], Y1 = hbf[t][q1][1];
        plswap(X0, Y0);
        plswap(X1, Y1);
        u32x4 fv = { X0, X1, Y0, Y1 };
        bf16x8 hf = __builtin_bit_cast(bf16x8, fv);
        const short* wb = w2frag + s * 2048 + fslot;
#pragma unroll
        for (int tt = 0; tt < 4; ++tt) {
            bf16x8 w = *(const bf16x8*)(wb + tt * 512);
            acc2[tt] = __builtin_amdgcn_mfma_f32_32x32x16_bf16(hf, w, acc2[tt], 0, 0, 0);
        }
    }

#pragma unroll
    for (int r = 0; r < 16; ++r) {
        float s1 = acc2[0][r] + acc2[1][r] + acc2[2][r] + acc2[3][r];
        float s2 = acc2[0][r]*acc2[0][r] + acc2[1][r]*acc2[1][r]
                 + acc2[2][r]*acc2[2][r] + acc2[3][r]*acc2[3][r];
#pragma unroll
        for (int msk = 1; msk < 32; msk <<= 1) {
            s1 += __shfl_xor(s1, msk, 64);
            s2 += __shfl_xor(s2, msk, 64);
        }
        const float mu   = s1 * (1.0f / 128.0f);
        const float var  = s2 * (1.0f / 128.0f) - mu * mu;
        const float rstd = rsqrtf(var + 1e-5f);
        const int   m    = (r & 3) + 8 * (r >> 2) + 4 * hi;
        const int   eo   = ebase + m;
        if (eo < E) {
            float* po = out + (size_t)eo * DDIM;
#pragma unroll
            for (int tt = 0; tt < 4; ++tt) {
                float o = (acc2[tt][r] - mu) * rstd * gv[tt] + bv[tt];
                __builtin_nontemporal_store(o, po + 32 * tt + lo);
            }
        }
    }
}

extern "C" void kernel_launch(void* const* d_in, const int* in_sizes, int n_in,
                              void* d_out, int out_size, void* d_ws, size_t ws_size,
                              hipStream_t stream)
{
    const float* efeat    = (const float*)d_in[0];
    const float* src_feat = (const float*)d_in[1];
    const float* dst_feat = (const float*)d_in[2];
    const int*   src_idx  = (const int*)d_in[3];
    const int*   dst_idx  = (const int*)d_in[4];
    const float* w_efeat  = (const float*)d_in[5];
    const float* w_src    = (const float*)d_in[6];
    const float* w_dst    = (const float*)d_in[7];
    const float* b0       = (const float*)d_in[8];
    const float* w_out    = (const float*)d_in[9];
    const float* b_out    = (const float*)d_in[10];
    const float* ln_g     = (const float*)d_in[11];
    const float* ln_b     = (const float*)d_in[12];
    float* out = (float*)d_out;
    const int E    = in_sizes[3];
    const int nsrc = in_sizes[1] / DDIM;
    const int ndst = in_sizes[2] / DDIM;

    short* w1frag = (short*)d_ws;                              // 96 KB
    short* w2frag = (short*)((char*)d_ws + 24 * 128 * 16 * 2); // 32 KB
    const size_t tab_off = 128 * 1024;
    const size_t need = tab_off + ((size_t)nsrc + (size_t)ndst) * DDIM * 2;

    prep_weights<<<256, 256, 0, stream>>>(w_efeat, w_src, w_dst, w_out, w1frag, w2frag);

    const int nb = (E + 127) / 128;
    if (ws_size >= need) {
        short* tsrc = (short*)((char*)d_ws + tab_off);
        short* tdst = tsrc + (size_t)nsrc * DDIM;
        node_table<<<(nsrc + 127) / 128, 256, 0, stream>>>(src_feat, w1frag, 8,  tsrc, nsrc);
        node_table<<<(ndst + 127) / 128, 256, 0, stream>>>(dst_feat, w1frag, 16, tdst, ndst);
        edge_kernel_tab<<<nb, 256, 0, stream>>>(efeat, tsrc, tdst, src_idx, dst_idx,
                                                b0, b_out, ln_g, ln_b, w1frag, w2frag, out, E);
    } else {
        edge_kernel_fullk<<<nb, 256, 0, stream>>>(efeat, src_feat, dst_feat, src_idx, dst_idx,
                                                  b0, b_out, ln_g, ln_b, w1frag, w2frag, out, E);
    }
}